// Round 1
// baseline (64.552 us; speedup 1.0000x reference)
//
#include <hip/hip_runtime.h>
#include <cmath>

#define HH 512
#define WW 512
#define TILE 64
#define IMG_T 72   // TILE + 2*4 halo (blur2 + sobel1 + nms1)
#define HB_W 68    // hblur cols = TILE + 2*2
#define BL_T 68    // blurred tile = TILE + 2*2
#define MAG_T 66   // mag tile = TILE + 2*1
#define NTHREADS 256

struct Blur5 { float w[5]; };

// packed (dr+1), (dc+1) 2-bit LUTs for the 8 NMS directions
// OFFS = {(0,1),(-1,1),(-1,0),(-1,-1),(0,-1),(1,-1),(1,0),(1,1)}
#define DR_PACK 43265u
#define DC_PACK 36890u

__device__ __forceinline__ void canny_tile(
    const float* __restrict__ img, int base_r, int base_c,
    float* sA, float* sB, const Blur5& kb,
    float thin[16], float oriv[16])
{
  const int tid = threadIdx.x;

  // ---- Phase 1: stage img tile (+halo 4), zero padding outside image ----
  for (int idx = tid; idx < IMG_T * IMG_T; idx += NTHREADS) {
    int ir = idx / IMG_T, ic = idx - ir * IMG_T;
    int gr = base_r + ir - 4, gc = base_c + ic - 4;
    float v = 0.f;
    if ((unsigned)gr < HH && (unsigned)gc < WW) v = img[gr * WW + gc];
    sA[idx] = v;
  }
  __syncthreads();

  // ---- Phase 2: horizontal 5-tap blur -> sB [72][68] ----
  for (int idx = tid; idx < IMG_T * HB_W; idx += NTHREADS) {
    int r = idx / HB_W, c = idx - r * HB_W;
    const float* p = &sA[r * IMG_T + c];
    sB[idx] = kb.w[0]*p[0] + kb.w[1]*p[1] + kb.w[2]*p[2] + kb.w[3]*p[3] + kb.w[4]*p[4];
  }
  __syncthreads();

  // ---- Phase 3: vertical 5-tap blur -> sA [68][68]; zero outside image ----
  // (SAME conv: the 'blurred' array only exists inside the image; later convs
  //  pad it with zeros, so halo positions outside [0,512)^2 must be 0.)
  for (int idx = tid; idx < BL_T * BL_T; idx += NTHREADS) {
    int r = idx / BL_T, c = idx - r * BL_T;
    int gr = base_r + r - 2, gc = base_c + c - 2;
    float v = 0.f;
    if ((unsigned)gr < HH && (unsigned)gc < WW) {
      const float* p = &sB[r * HB_W + c];
      v = kb.w[0]*p[0] + kb.w[1]*p[HB_W] + kb.w[2]*p[2*HB_W]
        + kb.w[3]*p[3*HB_W] + kb.w[4]*p[4*HB_W];
    }
    sA[r * BL_T + c] = v;
  }
  __syncthreads();

  // ---- Phase 4a: sobel magnitude -> sB [66][66]; zero outside image ----
  for (int idx = tid; idx < MAG_T * MAG_T; idx += NTHREADS) {
    int r = idx / MAG_T, c = idx - r * MAG_T;
    int gr = base_r + r - 1, gc = base_c + c - 1;
    float m = 0.f;
    if ((unsigned)gr < HH && (unsigned)gc < WW) {
      const float* p = &sA[r * BL_T + c];
      float b00 = p[0],        b01 = p[1],          b02 = p[2];
      float b10 = p[BL_T],                          b12 = p[BL_T + 2];
      float b20 = p[2*BL_T],   b21 = p[2*BL_T + 1], b22 = p[2*BL_T + 2];
      float gx = (b02 - b00) + 2.f*(b12 - b10) + (b22 - b20);
      float gy = (b20 - b00) + 2.f*(b21 - b01) + (b22 - b02);
      m = sqrtf(gx*gx + gy*gy + 1e-12f);
    }
    sB[r * MAG_T + c] = m;
  }

  // ---- Phase 4b: per-center-pixel orientation (registers) ----
  const int cc = tid & 63;
  const int r0 = (tid >> 6) * 16;
  int ipos[16];
  #pragma unroll
  for (int i = 0; i < 16; ++i) {
    int r = r0 + i;
    const float* p = &sA[(r + 1) * BL_T + (cc + 1)];
    float b00 = p[0],        b01 = p[1],          b02 = p[2];
    float b10 = p[BL_T],                          b12 = p[BL_T + 2];
    float b20 = p[2*BL_T],   b21 = p[2*BL_T + 1], b22 = p[2*BL_T + 2];
    float gx = (b02 - b00) + 2.f*(b12 - b10) + (b22 - b20);
    float gy = (b20 - b00) + 2.f*(b21 - b01) + (b22 - b02);
    float deg = atan2f(gy, gx) * 57.295779513082323f;   // jnp.degrees
    float rc = rintf((deg + 180.0f) / 45.0f);           // jnp.round (half-even)
    oriv[i] = rc * 45.0f;
    ipos[i] = ((int)rc) & 7;
  }
  __syncthreads();

  // ---- Phase 5: NMS (directional neighbor diffs over zero-padded mag) ----
  #pragma unroll
  for (int i = 0; i < 16; ++i) {
    int r = r0 + i;
    int ip = ipos[i];
    int dr = (int)((DR_PACK >> (2 * ip)) & 3u) - 1;
    int dc = (int)((DC_PACK >> (2 * ip)) & 3u) - 1;
    float mc = sB[(r + 1) * MAG_T + (cc + 1)];
    float n1 = sB[(r + 1 + dr) * MAG_T + (cc + 1 + dc)];
    float n2 = sB[(r + 1 - dr) * MAG_T + (cc + 1 - dc)];
    float dp = mc - n1, dn = mc - n2;
    thin[i] = (fminf(dp, dn) > 0.f) ? mc : 0.f;
  }
  __syncthreads();
}

__global__ void __launch_bounds__(NTHREADS)
canny_loss_kernel(const float* __restrict__ X, const float* __restrict__ Y,
                  float* __restrict__ out, Blur5 kb)
{
  __shared__ float sA[IMG_T * IMG_T];
  __shared__ float sB[IMG_T * HB_W];
  __shared__ float red[NTHREADS / 64];

  const int b = blockIdx.y;
  const int base_r = (int)(blockIdx.x >> 3) * TILE;
  const int base_c = (int)(blockIdx.x & 7) * TILE;
  const float* xb = X + (size_t)b * HH * WW;
  const float* yb = Y + (size_t)b * HH * WW;

  float thin_x[16], ori_x[16], thin_y[16], ori_y[16];
  canny_tile(xb, base_r, base_c, sA, sB, kb, thin_x, ori_x);
  canny_tile(yb, base_r, base_c, sA, sB, kb, thin_y, ori_y);

  float s = 0.f;
  #pragma unroll
  for (int i = 0; i < 16; ++i)
    s += fabsf(thin_x[i] - thin_y[i]) + fabsf(ori_x[i] - ori_y[i]);

  // wave reduce (64 lanes), then cross-wave via LDS, one atomic per block
  #pragma unroll
  for (int off = 32; off >= 1; off >>= 1) s += __shfl_down(s, off, 64);
  const int lane = threadIdx.x & 63, wv = threadIdx.x >> 6;
  if (lane == 0) red[wv] = s;
  __syncthreads();
  if (threadIdx.x == 0) {
    float t = red[0] + red[1] + red[2] + red[3];
    atomicAdd(out, t * (1.0f / ((float)HH * (float)WW)));
  }
}

extern "C" void kernel_launch(void* const* d_in, const int* in_sizes, int n_in,
                              void* d_out, int out_size, void* d_ws, size_t ws_size,
                              hipStream_t stream)
{
  const float* X = (const float*)d_in[0];
  const float* Y = (const float*)d_in[1];
  float* out = (float*)d_out;

  hipMemsetAsync(out, 0, (size_t)out_size * sizeof(float), stream);

  // Gaussian 1D weights in double, cast to f32 (matches reference f64->f32 path)
  Blur5 kb;
  {
    double g[5], ssum = 0.0;
    for (int i = 0; i < 5; ++i) { double d = i - 2; g[i] = std::exp(-(d * d) / 2.0); ssum += g[i]; }
    for (int i = 0; i < 5; ++i) kb.w[i] = (float)(g[i] / ssum);
  }

  dim3 grid(64, 16);   // 8x8 tiles of 64x64 per image, 16 batch
  canny_loss_kernel<<<grid, NTHREADS, 0, stream>>>(X, Y, out, kb);
}